// Round 8
// baseline (782.759 us; speedup 1.0000x reference)
//
#include <hip/hip_runtime.h>

#define BDIM 8192
#define DDIM 256
#define NSLOTS 512

typedef __bf16 bf16x8 __attribute__((ext_vector_type(8)));
typedef float f32x4 __attribute__((ext_vector_type(4)));
typedef unsigned short u16x4 __attribute__((ext_vector_type(4)));

#define MEMF() asm volatile("" ::: "memory")
#define BARR()                       \
  do {                               \
    MEMF();                          \
    __builtin_amdgcn_s_barrier();    \
    MEMF();                          \
  } while (0)
#define VMW(n) asm volatile("s_waitcnt vmcnt(" #n ")" ::: "memory")

__device__ inline unsigned short f2bf(float f) {
  unsigned u = __float_as_uint(f);
  u += 0x7FFFu + ((u >> 16) & 1u);  // round-to-nearest-even
  return (unsigned short)(u >> 16);
}
__device__ inline float bf2f(unsigned short h) {
  return __uint_as_float(((unsigned)h) << 16);
}

// Direct global->LDS DMA, 16B/lane. LDS operand = wave-uniform base; HW
// scatters lane*16. Global source is per-lane (carries the swizzle).
__device__ inline void gload_lds16(const void* g, void* l) {
  __builtin_amdgcn_global_load_lds(
      (const __attribute__((address_space(1))) void*)g,
      (__attribute__((address_space(3))) void*)l, 16, 0, 0);
}

// ---------------------------------------------------------------------------
// Kernel 1: normalize rows and convert to bf16, once. One wave per row.
// Block 0 additionally zeroes the reduction slots and the done-counter.
// ---------------------------------------------------------------------------
__global__ __launch_bounds__(256) void norm_convert_kernel(
    const float* __restrict__ t, const float* __restrict__ v,
    unsigned short* __restrict__ tn, unsigned short* __restrict__ vn,
    float* __restrict__ slots, unsigned* __restrict__ cnt) {
  int wid = threadIdx.x >> 6, lane = threadIdx.x & 63;
  if (blockIdx.x == 0) {
    slots[threadIdx.x] = 0.0f;
    slots[threadIdx.x + 256] = 0.0f;
    if (threadIdx.x == 0) cnt[0] = 0u;
  }
  int row = blockIdx.x * 4 + wid;
  const float* src;
  unsigned short* dst;
  if (row < BDIM) {
    src = t + (size_t)row * DDIM;
    dst = tn + (size_t)row * DDIM;
  } else {
    int r = row - BDIM;
    src = v + (size_t)r * DDIM;
    dst = vn + (size_t)r * DDIM;
  }
  float4 x = reinterpret_cast<const float4*>(src)[lane];
  float ss = x.x * x.x + x.y * x.y + x.z * x.z + x.w * x.w;
  #pragma unroll
  for (int off = 1; off < 64; off <<= 1) ss += __shfl_xor(ss, off, 64);
  float sc = 1.0f / fmaxf(sqrtf(ss), 1e-12f);
  u16x4 w;
  w[0] = f2bf(x.x * sc); w[1] = f2bf(x.y * sc);
  w[2] = f2bf(x.z * sc); w[3] = f2bf(x.w * sc);
  reinterpret_cast<u16x4*>(dst)[lane] = w;
}

// ---------------------------------------------------------------------------
// Kernel 2: 512x512-tile bf16 GEMM, 16 waves (4Mx4N), wave-tile 128x128,
// BK=32, double-buffered LDS (128KB), ONE VMW(0)+BARR per K-tile.
//
// ROUND-8 RATIONALE:
//  - 256 blocks on 256 CUs = ONE round: the exposed per-round prologue that
//    R6 paid 4x is paid once. Staged L2 traffic 268MB -> 64MB (4x reuse).
//  - 16 waves = 4/SIMD: latency hiding that R7's 1/SIMD lacked, with the
//    same 15.6 B/kFLOP LDS-read ratio R7 bought.
//  - Per SIMD per K-tile: 256 MFMA ~5.0k cyc >> LDS reads ~1.6k cyc
//    (4-way read conflicts from 64B rows accepted: 1.58x on a minor term)
//    >> DMA 64KB (~13 B/cyc/CU). Compute-dominated by design.
//  - acc[8][8] f32x4 = 256 regs + ~100 frag/addr < 512/wave unified budget
//    at 4 waves/EU (launch_bounds(1024,4)).
// Epilogue is position-blind (sum of 0.7*relu(s)^2): ANY consistent A/B
// fragment addressing yields a permuted-but-complete tile -> sum invariant.
// 2D panel-rectangle XCD swizzle: XCD owns 8x4 of the 16x16 panel grid
// (A 2MB + B 1MB < 4MB L2, all concurrent in the single round).
// LDS XOR swizzle involution: granule16' = granule16 ^ (row&3) on the
// per-lane GLOBAL source (DMA dest linear) and on the ds_read address.
// ---------------------------------------------------------------------------
__global__ __launch_bounds__(1024, 4) void loss_kernel(
    const unsigned short* __restrict__ tn,
    const unsigned short* __restrict__ vn, float* __restrict__ slots) {
  __shared__ unsigned short Asb[2][16384];  // [buf][512 rows][32 cols] 32KB
  __shared__ unsigned short Bsb[2][16384];
  __shared__ float rbuf[16];

  const int tid = threadIdx.x;
  const int lane = tid & 63;
  const int wid = tid >> 6;   // 0..15
  const int l15 = lane & 15;
  const int l4 = lane >> 4;   // 0..3
  const int wm = wid >> 2;    // 0..3: wave's 128-row quarter
  const int wn = wid & 3;     // 0..3: wave's 128-col quarter

  // XCD swizzle over the 16x16 panel grid: xcd -> 8x4 rectangle.
  const int flat = blockIdx.x;          // 0..255
  const int xcd = flat & 7;
  const int s = flat >> 3;              // 0..31
  const int rowp = (xcd >> 2) * 8 + (s >> 2);  // 0..15
  const int colp = (xcd & 3) * 4 + (s & 3);    // 0..15
  const int rowBase = rowp * 512;
  const int colBase = colp * 512;

  // Staging: [512][32]-short tiles; 1024 threads x 16B = 16KB per DMA set
  // (256 rows); 2 sets per matrix per K-tile. thread -> row tid>>2,
  // granule16 tid&3; source granule pre-swizzled with row&3.
  const int sg = (tid & 3) ^ ((tid >> 2) & 3);
  const unsigned short* gAsrc =
      tn + (size_t)(rowBase + (tid >> 2)) * DDIM + sg * 8;
  const unsigned short* gBsrc =
      vn + (size_t)(colBase + (tid >> 2)) * DDIM + sg * 8;
  const int ldsW = wid * 512;  // wave covers rows wid*16..+15 (512 shorts)

  auto stA = [&](int ob, int half, int kt) {
    gload_lds16(gAsrc + (size_t)half * 256 * DDIM + kt * 32,
                &Asb[ob][half * 8192 + ldsW]);
  };
  auto stB = [&](int ob, int half, int kt) {
    gload_lds16(gBsrc + (size_t)half * 256 * DDIM + kt * 32,
                &Bsb[ob][half * 8192 + ldsW]);
  };

  f32x4 acc[8][8];
  #pragma unroll
  for (int i = 0; i < 8; ++i)
    #pragma unroll
    for (int j = 0; j < 8; ++j) acc[i][j] = (f32x4)(0.0f);

  // Prologue: stage tile 0 into buf0, drain, barrier.
  stA(0, 0, 0); stA(0, 1, 0); stB(0, 0, 0); stB(0, 1, 0);
  VMW(0);
  BARR();

  #pragma unroll
  for (int t = 0; t < 8; ++t) {  // K-tiles (K=256, BK=32)
    const int cur = t & 1, ob = cur ^ 1, kt = t + 1;
    // Issue-early: 4 prefetch DMAs for tile t+1 into the dead buffer.
    if (t < 7) {
      stA(ob, 0, kt); stA(ob, 1, kt); stB(ob, 0, kt); stB(ob, 1, kt);
    }
    // 16 ds_read_b128 (A 8, B 8), then 64 MFMA. One b128 per fragment:
    // granule = l4, swizzled gg = l4 ^ (row&3), row&3 == l15&3.
    bf16x8 af[8], bv[8];
    #pragma unroll
    for (int mm = 0; mm < 8; ++mm) {
      const int row = wm * 128 + mm * 16 + l15;
      const int gg = l4 ^ (l15 & 3);
      af[mm] = *reinterpret_cast<const bf16x8*>(&Asb[cur][row * 32 + gg * 8]);
    }
    #pragma unroll
    for (int nn = 0; nn < 8; ++nn) {
      const int row = wn * 128 + nn * 16 + l15;
      const int gg = l4 ^ (l15 & 3);
      bv[nn] = *reinterpret_cast<const bf16x8*>(&Bsb[cur][row * 32 + gg * 8]);
    }
    __builtin_amdgcn_s_setprio(1);
    #pragma unroll
    for (int mm = 0; mm < 8; ++mm)
      #pragma unroll
      for (int nn = 0; nn < 8; ++nn)
        acc[mm][nn] = __builtin_amdgcn_mfma_f32_16x16x32_bf16(
            af[mm], bv[nn], acc[mm][nn], 0, 0, 0);
    __builtin_amdgcn_s_setprio(0);
    // Tile boundary: next tile's staging must be complete in every wave.
    if (t < 7) {
      VMW(0);
      BARR();
    }
  }

  // Position-blind epilogue: 0.7*max(s,0)^2 for every element.
  float lsum = 0.0f;
  #pragma unroll
  for (int m = 0; m < 8; ++m)
    #pragma unroll
    for (int n = 0; n < 8; ++n)
      #pragma unroll
      for (int r2 = 0; r2 < 4; ++r2) {
        float u = fmaxf(acc[m][n][r2], 0.0f);
        lsum = fmaf(u, u, lsum);
      }
  lsum *= 0.7f;  // LAMBDA_NEG
  #pragma unroll
  for (int off = 1; off < 64; off <<= 1) lsum += __shfl_xor(lsum, off, 64);
  if (lane == 0) rbuf[wid] = lsum;
  __syncthreads();
  if (tid == 0) {
    float sacc = 0.0f;
    #pragma unroll
    for (int w = 0; w < 16; ++w) sacc += rbuf[w];
    atomicAdd(&slots[flat & (NSLOTS - 1)], sacc);
  }
}

// ---------------------------------------------------------------------------
// Kernel 3: sparse fixups, one wave per row; fused final reduction. The last
// block to finish (device-scope done-counter) sums the slots with scoped
// loads and writes out. Safe: loss_kernel completed before corr starts
// (stream order), and every corr block fences before bumping the counter.
// ---------------------------------------------------------------------------
__global__ __launch_bounds__(256) void corr_kernel(
    const unsigned short* __restrict__ tn,
    const unsigned short* __restrict__ vn, const int* __restrict__ sidx,
    float* __restrict__ slots, unsigned* __restrict__ cnt,
    float* __restrict__ out) {
  __shared__ int lastf;
  __shared__ float rb[4];
  int wid = threadIdx.x >> 6, lane = threadIdx.x & 63;
  int i = blockIdx.x * 4 + wid;

  u16x4 ta = reinterpret_cast<const u16x4*>(tn + (size_t)i * DDIM)[lane];
  float t0 = bf2f(ta[0]), t1 = bf2f(ta[1]), t2 = bf2f(ta[2]), t3 = bf2f(ta[3]);

  int j0 = sidx[(size_t)i * 3 + 0];
  int j1 = sidx[(size_t)i * 3 + 1];
  int j2 = sidx[(size_t)i * 3 + 2];
  bool v0 = (j0 >= 0) & (j0 < BDIM) & (j0 != i);
  bool v1 = (j1 >= 0) & (j1 < BDIM) & (j1 != i) & !(v0 & (j1 == j0));
  bool v2 = (j2 >= 0) & (j2 < BDIM) & (j2 != i) & !(v0 & (j2 == j0)) &
            !(v1 & (j2 == j1));

  float corr = 0.0f;
  {  // diagonal: replace 0.7*max(s,0)^2 with (s-1)^2
    u16x4 va = reinterpret_cast<const u16x4*>(vn + (size_t)i * DDIM)[lane];
    float d = t0 * bf2f(va[0]) + t1 * bf2f(va[1]) + t2 * bf2f(va[2]) +
              t3 * bf2f(va[3]);
    #pragma unroll
    for (int off = 1; off < 64; off <<= 1) d += __shfl_xor(d, off, 64);
    float u = fmaxf(d, 0.0f);
    corr += (d - 1.0f) * (d - 1.0f) - 0.7f * u * u;
  }
  int jj[3] = {j0, j1, j2};
  bool vv[3] = {v0, v1, v2};
  #pragma unroll
  for (int k = 0; k < 3; ++k) {
    int j = vv[k] ? jj[k] : i;  // safe address; discarded if invalid
    u16x4 va = reinterpret_cast<const u16x4*>(vn + (size_t)j * DDIM)[lane];
    float d = t0 * bf2f(va[0]) + t1 * bf2f(va[1]) + t2 * bf2f(va[2]) +
              t3 * bf2f(va[3]);
    #pragma unroll
    for (int off = 1; off < 64; off <<= 1) d += __shfl_xor(d, off, 64);
    if (vv[k]) {
      float up = fmaxf(0.7f - d, 0.0f);
      float un = fmaxf(d, 0.0f);
      corr += 0.7f * (up * up - un * un);
    }
  }
  if (lane == 0) atomicAdd(&slots[i & (NSLOTS - 1)], corr);

  // ---- fused finalize: last block sums the slots -> out ----
  __syncthreads();
  if (threadIdx.x == 0) {
    __threadfence();  // slot adds visible before counter bump
    unsigned old = atomicAdd(cnt, 1u);
    lastf = (old == 2047u) ? 1 : 0;
  }
  __syncthreads();
  if (lastf) {
    __threadfence();
    int tid = threadIdx.x;
    float sv = __hip_atomic_load(&slots[tid], __ATOMIC_RELAXED,
                                 __HIP_MEMORY_SCOPE_AGENT) +
               __hip_atomic_load(&slots[tid + 256], __ATOMIC_RELAXED,
                                 __HIP_MEMORY_SCOPE_AGENT);
    #pragma unroll
    for (int off = 1; off < 64; off <<= 1) sv += __shfl_xor(sv, off, 64);
    if ((tid & 63) == 0) rb[tid >> 6] = sv;
    __syncthreads();
    if (tid == 0) out[0] = rb[0] + rb[1] + rb[2] + rb[3];
  }
}

extern "C" void kernel_launch(void* const* d_in, const int* in_sizes, int n_in,
                              void* d_out, int out_size, void* d_ws,
                              size_t ws_size, hipStream_t stream) {
  const float* t = (const float*)d_in[0];
  const float* v = (const float*)d_in[1];
  const int* sidx = (const int*)d_in[2];
  float* out = (float*)d_out;
  float* slots = (float*)d_ws;                        // 512 floats
  unsigned* cnt = (unsigned*)((char*)d_ws + 2048);    // done-counter
  unsigned short* tn = (unsigned short*)((char*)d_ws + 4096);  // 4 MB
  unsigned short* vn = tn + (size_t)BDIM * DDIM;               // 4 MB

  norm_convert_kernel<<<4096, 256, 0, stream>>>(t, v, tn, vn, slots, cnt);
  loss_kernel<<<256, 1024, 0, stream>>>(tn, vn, slots);
  corr_kernel<<<2048, 256, 0, stream>>>(tn, vn, sidx, slots, cnt, out);
}

// Round 9
// 129.809 us; speedup vs baseline: 6.0301x; 6.0301x over previous
//
#include <hip/hip_runtime.h>

#define BDIM 8192
#define DDIM 256
#define NSLOTS 512

typedef __bf16 bf16x8 __attribute__((ext_vector_type(8)));
typedef float f32x4 __attribute__((ext_vector_type(4)));
typedef unsigned short u16x4 __attribute__((ext_vector_type(4)));

#define MEMF() asm volatile("" ::: "memory")
#define BARR()                       \
  do {                               \
    MEMF();                          \
    __builtin_amdgcn_s_barrier();    \
    MEMF();                          \
  } while (0)
#define VMW(n) asm volatile("s_waitcnt vmcnt(" #n ")" ::: "memory")

__device__ inline unsigned short f2bf(float f) {
  unsigned u = __float_as_uint(f);
  u += 0x7FFFu + ((u >> 16) & 1u);  // round-to-nearest-even
  return (unsigned short)(u >> 16);
}
__device__ inline float bf2f(unsigned short h) {
  return __uint_as_float(((unsigned)h) << 16);
}

// Direct global->LDS DMA, 16B/lane. LDS operand = wave-uniform base; HW
// scatters lane*16. Global source is per-lane (carries the swizzle).
__device__ inline void gload_lds16(const void* g, void* l) {
  __builtin_amdgcn_global_load_lds(
      (const __attribute__((address_space(1))) void*)g,
      (__attribute__((address_space(3))) void*)l, 16, 0, 0);
}

// ---------------------------------------------------------------------------
// Kernel 1: normalize rows and convert to bf16, once. One wave per row.
// Block 0 additionally zeroes the reduction slots and the done-counter.
// ---------------------------------------------------------------------------
__global__ __launch_bounds__(256) void norm_convert_kernel(
    const float* __restrict__ t, const float* __restrict__ v,
    unsigned short* __restrict__ tn, unsigned short* __restrict__ vn,
    float* __restrict__ slots, unsigned* __restrict__ cnt) {
  int wid = threadIdx.x >> 6, lane = threadIdx.x & 63;
  if (blockIdx.x == 0) {
    slots[threadIdx.x] = 0.0f;
    slots[threadIdx.x + 256] = 0.0f;
    if (threadIdx.x == 0) cnt[0] = 0u;
  }
  int row = blockIdx.x * 4 + wid;
  const float* src;
  unsigned short* dst;
  if (row < BDIM) {
    src = t + (size_t)row * DDIM;
    dst = tn + (size_t)row * DDIM;
  } else {
    int r = row - BDIM;
    src = v + (size_t)r * DDIM;
    dst = vn + (size_t)r * DDIM;
  }
  float4 x = reinterpret_cast<const float4*>(src)[lane];
  float ss = x.x * x.x + x.y * x.y + x.z * x.z + x.w * x.w;
  #pragma unroll
  for (int off = 1; off < 64; off <<= 1) ss += __shfl_xor(ss, off, 64);
  float sc = 1.0f / fmaxf(sqrtf(ss), 1e-12f);
  u16x4 w;
  w[0] = f2bf(x.x * sc); w[1] = f2bf(x.y * sc);
  w[2] = f2bf(x.z * sc); w[3] = f2bf(x.w * sc);
  reinterpret_cast<u16x4*>(dst)[lane] = w;
}

// ---------------------------------------------------------------------------
// Kernel 2: 256x256-tile bf16 GEMM, 8 waves (2Mx4N), wave-tile 128x64,
// BK=64, one barrier per K-tile (round-5/6 schedule).
//
// ROUND-9 CHANGE: A operand read DIRECTLY from global (no LDS staging).
// Rationale: with the 2D XCD panel swizzle the A panel is L2-resident
// (R7 proved FETCH_SIZE collapses to 13MB), and A was the bulk of the LDS
// read traffic (128KB of 192KB per K-tile per CU). LDS reads drop to B-only
// 64KB (~0.75k cyc) and A moves to L2/L1 (~1k cyc; 4 lanes/row form 64B
// segments; 4 waves share each A half -> L1 broadcast), so MFMA (~2.5k cyc
// per K-tile per CU) dominates every other pipe >=2.5x. Registers: acc 128
// + frags 64 + addr ~230 -> fits 2 waves/SIMD (the R8 lesson: 1024-thread
// blocks cap VGPR at 128/wave by construction -> acc spills; stay at 512).
//
// B path unchanged: LDS XOR swizzle involution granule' = granule^(row&7)
// on per-lane global source (DMA dest linear) + ds_read address; issue-early
// 4 DMAs into the dead buffer; VMW(0)+BARR only at tile boundary
// (residual-only wait). Epilogue position-blind (sum of 0.7*relu(s)^2 is
// invariant to fragment permutation); diag/semi fixed up by corr_kernel.
// ---------------------------------------------------------------------------
__global__ __launch_bounds__(512) void loss_kernel(
    const unsigned short* __restrict__ tn,
    const unsigned short* __restrict__ vn, float* __restrict__ slots) {
  __shared__ unsigned short Bsb[2][16384];  // [buf][256 rows][64 cols] 32KB
  __shared__ float rbuf[8];

  const int tid = threadIdx.x;
  const int lane = tid & 63;
  const int wid = tid >> 6;
  const int l15 = lane & 15;
  const int l4 = lane >> 4;
  const int wm = wid >> 2;  // 0..1: wave's 128-row half
  const int wn = wid & 3;   // 0..3: wave's 64-col quarter

  // 2D panel-rectangle XCD swizzle (1024 blocks, 8 XCDs): XCD (xi,xj) owns
  // a 16x8 panel rectangle; round r covers a 4x8 sub-rectangle.
  const int flat = blockIdx.x;
  const int xcd = flat & 7;
  const int s = flat >> 3;   // 0..127 within XCD
  const int r = s >> 5;      // round 0..3 (32 CUs/XCD)
  const int p = s & 31;      // position in the 4x8 rectangle
  const int rowp = (xcd >> 2) * 16 + r * 4 + (p >> 3);  // 0..31
  const int colp = (xcd & 3) * 8 + (p & 7);             // 0..31
  const int rowBase = rowp * 256;
  const int colBase = colp * 256;

  // B staging: one region = 64 rows (512 threads x 16B = 8KB).
  const int sg = (tid & 7) ^ ((tid >> 3) & 7);
  const unsigned short* gBsrc =
      vn + (size_t)(colBase + (tid >> 3)) * DDIM + sg * 8;
  const int ldsStage = wid * 512;  // shorts; wave-uniform base

  auto stB = [&](int ob, int rg, int kt) {
    gload_lds16(gBsrc + (size_t)rg * 64 * DDIM + kt * 64,
                &Bsb[ob][rg * 4096 + ldsStage]);
  };

  // A direct-global per-lane base: row = rowBase + wm*128 + l15,
  // k-granule base = l4*8. Fragment (mh,mm,kk) = pA + (mh*64+mm*16)*DDIM
  // + t*64 + kk*32  -> identical bytes to the old LDS path.
  const unsigned short* pA =
      tn + (size_t)(rowBase + wm * 128 + l15) * DDIM + l4 * 8;

  f32x4 acc[8][4];
  #pragma unroll
  for (int i = 0; i < 8; ++i)
    #pragma unroll
    for (int j = 0; j < 4; ++j) acc[i][j] = (f32x4)(0.0f);

  bf16x8 af[4][2], bv0[2][2], bv1[2][2];

  auto readAg = [&](int t, int mh) {
    #pragma unroll
    for (int mm = 0; mm < 4; ++mm)
      #pragma unroll
      for (int kk = 0; kk < 2; ++kk)
        af[mm][kk] = *reinterpret_cast<const bf16x8*>(
            pA + (size_t)(mh * 64 + mm * 16) * DDIM + t * 64 + kk * 32);
  };
  auto readB = [&](int cur, int nh, bf16x8 (&bv)[2][2]) {
    #pragma unroll
    for (int nn = 0; nn < 2; ++nn) {
      const int row = wn * 64 + (nh * 2 + nn) * 16 + l15;
      #pragma unroll
      for (int kk = 0; kk < 2; ++kk) {
        const int gg = (kk * 4 + l4) ^ (l15 & 7);
        bv[nn][kk] =
            *reinterpret_cast<const bf16x8*>(&Bsb[cur][row * 64 + gg * 8]);
      }
    }
  };
  auto mfmaQ = [&](int mh, int nh, bf16x8 (&bv)[2][2]) {
    __builtin_amdgcn_s_setprio(1);
    #pragma unroll
    for (int mm = 0; mm < 4; ++mm)
      #pragma unroll
      for (int nn = 0; nn < 2; ++nn)
        #pragma unroll
        for (int kk = 0; kk < 2; ++kk)
          acc[mh * 4 + mm][nh * 2 + nn] =
              __builtin_amdgcn_mfma_f32_16x16x32_bf16(
                  af[mm][kk], bv[nn][kk], acc[mh * 4 + mm][nh * 2 + nn], 0, 0,
                  0);
    __builtin_amdgcn_s_setprio(0);
  };

  // Prologue: stage B tile 0 into buf0, drain, barrier.
  stB(0, 0, 0); stB(0, 1, 0); stB(0, 2, 0); stB(0, 3, 0);
  VMW(0);
  BARR();

  #pragma unroll
  for (int t = 0; t < 4; ++t) {  // K-tiles (K=256, BK=64)
    const int cur = t & 1, ob = cur ^ 1, kt = t + 1;
    // Issue-early: 4 B prefetch DMAs for tile t+1 (dead buffer).
    if (t < 3) {
      stB(ob, 0, kt); stB(ob, 1, kt); stB(ob, 2, kt); stB(ob, 3, kt);
    }
    // Straight-line reads + MFMA; compiler emits counted lgkm/vm waits,
    // the two skewed waves per SIMD cross-cover loads vs MFMA.
    readAg(t, 0);
    readB(cur, 0, bv0);
    readB(cur, 1, bv1);
    mfmaQ(0, 0, bv0);
    mfmaQ(0, 1, bv1);
    readAg(t, 1);
    mfmaQ(1, 1, bv1);
    mfmaQ(1, 0, bv0);
    // Tile boundary: next tile's B staging must be complete in every wave.
    if (t < 3) {
      VMW(0);
      BARR();
    }
  }

  // Position-blind epilogue: 0.7*max(s,0)^2 for every element.
  float lsum = 0.0f;
  #pragma unroll
  for (int m = 0; m < 8; ++m)
    #pragma unroll
    for (int n = 0; n < 4; ++n)
      #pragma unroll
      for (int r2 = 0; r2 < 4; ++r2) {
        float u = fmaxf(acc[m][n][r2], 0.0f);
        lsum = fmaf(u, u, lsum);
      }
  lsum *= 0.7f;  // LAMBDA_NEG
  #pragma unroll
  for (int off = 1; off < 64; off <<= 1) lsum += __shfl_xor(lsum, off, 64);
  if (lane == 0) rbuf[wid] = lsum;
  __syncthreads();
  if (tid == 0) {
    float sacc = 0.0f;
    #pragma unroll
    for (int w = 0; w < 8; ++w) sacc += rbuf[w];
    atomicAdd(&slots[flat & (NSLOTS - 1)], sacc);
  }
}

// ---------------------------------------------------------------------------
// Kernel 3: sparse fixups, one wave per row; fused final reduction. The last
// block to finish (device-scope done-counter) sums the slots with scoped
// loads and writes out. Safe: loss_kernel completed before corr starts
// (stream order), and every corr block fences before bumping the counter.
// ---------------------------------------------------------------------------
__global__ __launch_bounds__(256) void corr_kernel(
    const unsigned short* __restrict__ tn,
    const unsigned short* __restrict__ vn, const int* __restrict__ sidx,
    float* __restrict__ slots, unsigned* __restrict__ cnt,
    float* __restrict__ out) {
  __shared__ int lastf;
  __shared__ float rb[4];
  int wid = threadIdx.x >> 6, lane = threadIdx.x & 63;
  int i = blockIdx.x * 4 + wid;

  u16x4 ta = reinterpret_cast<const u16x4*>(tn + (size_t)i * DDIM)[lane];
  float t0 = bf2f(ta[0]), t1 = bf2f(ta[1]), t2 = bf2f(ta[2]), t3 = bf2f(ta[3]);

  int j0 = sidx[(size_t)i * 3 + 0];
  int j1 = sidx[(size_t)i * 3 + 1];
  int j2 = sidx[(size_t)i * 3 + 2];
  bool v0 = (j0 >= 0) & (j0 < BDIM) & (j0 != i);
  bool v1 = (j1 >= 0) & (j1 < BDIM) & (j1 != i) & !(v0 & (j1 == j0));
  bool v2 = (j2 >= 0) & (j2 < BDIM) & (j2 != i) & !(v0 & (j2 == j0)) &
            !(v1 & (j2 == j1));

  float corr = 0.0f;
  {  // diagonal: replace 0.7*max(s,0)^2 with (s-1)^2
    u16x4 va = reinterpret_cast<const u16x4*>(vn + (size_t)i * DDIM)[lane];
    float d = t0 * bf2f(va[0]) + t1 * bf2f(va[1]) + t2 * bf2f(va[2]) +
              t3 * bf2f(va[3]);
    #pragma unroll
    for (int off = 1; off < 64; off <<= 1) d += __shfl_xor(d, off, 64);
    float u = fmaxf(d, 0.0f);
    corr += (d - 1.0f) * (d - 1.0f) - 0.7f * u * u;
  }
  int jj[3] = {j0, j1, j2};
  bool vv[3] = {v0, v1, v2};
  #pragma unroll
  for (int k = 0; k < 3; ++k) {
    int j = vv[k] ? jj[k] : i;  // safe address; discarded if invalid
    u16x4 va = reinterpret_cast<const u16x4*>(vn + (size_t)j * DDIM)[lane];
    float d = t0 * bf2f(va[0]) + t1 * bf2f(va[1]) + t2 * bf2f(va[2]) +
              t3 * bf2f(va[3]);
    #pragma unroll
    for (int off = 1; off < 64; off <<= 1) d += __shfl_xor(d, off, 64);
    if (vv[k]) {
      float up = fmaxf(0.7f - d, 0.0f);
      float un = fmaxf(d, 0.0f);
      corr += 0.7f * (up * up - un * un);
    }
  }
  if (lane == 0) atomicAdd(&slots[i & (NSLOTS - 1)], corr);

  // ---- fused finalize: last block sums the slots -> out ----
  __syncthreads();
  if (threadIdx.x == 0) {
    __threadfence();  // slot adds visible before counter bump
    unsigned old = atomicAdd(cnt, 1u);
    lastf = (old == 2047u) ? 1 : 0;
  }
  __syncthreads();
  if (lastf) {
    __threadfence();
    int tid = threadIdx.x;
    float sv = __hip_atomic_load(&slots[tid], __ATOMIC_RELAXED,
                                 __HIP_MEMORY_SCOPE_AGENT) +
               __hip_atomic_load(&slots[tid + 256], __ATOMIC_RELAXED,
                                 __HIP_MEMORY_SCOPE_AGENT);
    #pragma unroll
    for (int off = 1; off < 64; off <<= 1) sv += __shfl_xor(sv, off, 64);
    if ((tid & 63) == 0) rb[tid >> 6] = sv;
    __syncthreads();
    if (tid == 0) out[0] = rb[0] + rb[1] + rb[2] + rb[3];
  }
}

extern "C" void kernel_launch(void* const* d_in, const int* in_sizes, int n_in,
                              void* d_out, int out_size, void* d_ws,
                              size_t ws_size, hipStream_t stream) {
  const float* t = (const float*)d_in[0];
  const float* v = (const float*)d_in[1];
  const int* sidx = (const int*)d_in[2];
  float* out = (float*)d_out;
  float* slots = (float*)d_ws;                        // 512 floats
  unsigned* cnt = (unsigned*)((char*)d_ws + 2048);    // done-counter
  unsigned short* tn = (unsigned short*)((char*)d_ws + 4096);  // 4 MB
  unsigned short* vn = tn + (size_t)BDIM * DDIM;               // 4 MB

  norm_convert_kernel<<<4096, 256, 0, stream>>>(t, v, tn, vn, slots, cnt);
  loss_kernel<<<1024, 512, 0, stream>>>(tn, vn, slots);
  corr_kernel<<<2048, 256, 0, stream>>>(tn, vn, sidx, slots, cnt, out);
}

// Round 10
// 72.524 us; speedup vs baseline: 10.7931x; 1.7899x over previous
//
#include <hip/hip_runtime.h>

#define BDIM 8192
#define DDIM 256
#define NSLOTS 512

typedef __bf16 bf16x8 __attribute__((ext_vector_type(8)));
typedef float f32x16 __attribute__((ext_vector_type(16)));
typedef unsigned short u16x4 __attribute__((ext_vector_type(4)));

#define MEMF() asm volatile("" ::: "memory")
#define BARR()                       \
  do {                               \
    MEMF();                          \
    __builtin_amdgcn_s_barrier();    \
    MEMF();                          \
  } while (0)
#define VMW(n) asm volatile("s_waitcnt vmcnt(" #n ")" ::: "memory")

__device__ inline unsigned short f2bf(float f) {
  unsigned u = __float_as_uint(f);
  u += 0x7FFFu + ((u >> 16) & 1u);  // round-to-nearest-even
  return (unsigned short)(u >> 16);
}
__device__ inline float bf2f(unsigned short h) {
  return __uint_as_float(((unsigned)h) << 16);
}

// Direct global->LDS DMA, 16B/lane. LDS operand = wave-uniform base; HW
// scatters lane*16. Global source is per-lane (carries the swizzle).
__device__ inline void gload_lds16(const void* g, void* l) {
  __builtin_amdgcn_global_load_lds(
      (const __attribute__((address_space(1))) void*)g,
      (__attribute__((address_space(3))) void*)l, 16, 0, 0);
}

// ---------------------------------------------------------------------------
// Kernel 1: normalize rows and convert to bf16, once. One wave per row.
// Block 0 additionally zeroes the reduction slots and the done-counter.
// ---------------------------------------------------------------------------
__global__ __launch_bounds__(256) void norm_convert_kernel(
    const float* __restrict__ t, const float* __restrict__ v,
    unsigned short* __restrict__ tn, unsigned short* __restrict__ vn,
    float* __restrict__ slots, unsigned* __restrict__ cnt) {
  int wid = threadIdx.x >> 6, lane = threadIdx.x & 63;
  if (blockIdx.x == 0) {
    slots[threadIdx.x] = 0.0f;
    slots[threadIdx.x + 256] = 0.0f;
    if (threadIdx.x == 0) cnt[0] = 0u;
  }
  int row = blockIdx.x * 4 + wid;
  const float* src;
  unsigned short* dst;
  if (row < BDIM) {
    src = t + (size_t)row * DDIM;
    dst = tn + (size_t)row * DDIM;
  } else {
    int r = row - BDIM;
    src = v + (size_t)r * DDIM;
    dst = vn + (size_t)r * DDIM;
  }
  float4 x = reinterpret_cast<const float4*>(src)[lane];
  float ss = x.x * x.x + x.y * x.y + x.z * x.z + x.w * x.w;
  #pragma unroll
  for (int off = 1; off < 64; off <<= 1) ss += __shfl_xor(ss, off, 64);
  float sc = 1.0f / fmaxf(sqrtf(ss), 1e-12f);
  u16x4 w;
  w[0] = f2bf(x.x * sc); w[1] = f2bf(x.y * sc);
  w[2] = f2bf(x.z * sc); w[3] = f2bf(x.w * sc);
  reinterpret_cast<u16x4*>(dst)[lane] = w;
}

// ---------------------------------------------------------------------------
// Kernel 2 (fused): blocks 0..1023 = 256x256-tile bf16 GEMM (R6 structure:
// 8 waves 2Mx4N, wave-tile 128x64, BK=64, A+B staged via gload_lds with
// XOR-swizzle involution, issue-early prefetch into the dead buffer, ONE
// VMW(0)+BARR per K-tile, 2D panel-rectangle XCD swizzle). Blocks
// 1024..1151 = sparse corr fixups (64 rows/block), dispatched last so they
// run on freed CUs under the final GEMM round. Last of 1152 blocks sums the
// slots -> out (device-scope done-counter).
//
// ROUND-10 GEMM CHANGES (sync structure untouched):
//  - 32x32x16 MFMA: same LDS read volume (reads ~ wave-tile perimeter),
//    HALF the MFMA instructions, 15% higher ceiling (2382 vs 2075 TF).
//    Read pattern row=lane&31, k-octet=lane>>5, gg=(ks*2+l32)^(lane&7):
//    8-lane groups XOR onto 8 distinct granules -> conflict-free.
//    Position-blind epilogue + identical A/B addressing make any
//    lane-permutation of the tile sum-invariant; corr is position-exact.
//  - Compile-time read addressing: 8 per-lane base pointers (A/B x ks),
//    every ds_read = base + IMM (cur*32768 + mt*4096 <= 45056 < 64KB).
//    Kills the ~21% VALUBusy address tax that serialized with MFMA issue.
// ---------------------------------------------------------------------------
__global__ __launch_bounds__(512) void fused_kernel(
    const unsigned short* __restrict__ tn,
    const unsigned short* __restrict__ vn, const int* __restrict__ sidx,
    float* __restrict__ slots, unsigned* __restrict__ cnt,
    float* __restrict__ out) {
  __shared__ unsigned short Asb[2][16384];  // [buf][256 rows][64 cols]
  __shared__ unsigned short Bsb[2][16384];
  __shared__ float rbuf[8];
  __shared__ int lastf;

  const int tid = threadIdx.x;
  const int bid = blockIdx.x;
  const int lane = tid & 63;
  const int wid = tid >> 6;

  if (bid < 1024) {
    // ------------------------- GEMM role -------------------------
    const int l31 = lane & 31;
    const int l7 = lane & 7;
    const int l32 = lane >> 5;
    const int wm = wid >> 2;  // 0..1: wave's 128-row half
    const int wn = wid & 3;   // 0..3: wave's 64-col quarter

    // 2D panel-rectangle XCD swizzle: XCD owns a 16x8 panel rectangle;
    // round r covers a 4x8 sub-rectangle (A 512KB + B 1MB < 4MB L2).
    const int xcd = bid & 7;
    const int s = bid >> 3;
    const int r = s >> 5;
    const int p = s & 31;
    const int rowp = (xcd >> 2) * 16 + r * 4 + (p >> 3);
    const int colp = (xcd & 3) * 8 + (p & 7);
    const int rowBase = rowp * 256;
    const int colBase = colp * 256;

    // Staging: one region = 64 rows (512 threads x 16B = 8KB); source
    // granule pre-swizzled (sg) so linear DMA dest yields swizzled LDS.
    const int sg = (tid & 7) ^ ((tid >> 3) & 7);
    const unsigned short* gAsrc =
        tn + (size_t)(rowBase + (tid >> 3)) * DDIM + sg * 8;
    const unsigned short* gBsrc =
        vn + (size_t)(colBase + (tid >> 3)) * DDIM + sg * 8;
    const int ldsStage = wid * 512;  // shorts; wave-uniform base

    auto stA = [&](int ob, int rg, int kt) {
      gload_lds16(gAsrc + (size_t)rg * 64 * DDIM + kt * 64,
                  &Asb[ob][rg * 4096 + ldsStage]);
    };
    auto stB = [&](int ob, int rg, int kt) {
      gload_lds16(gBsrc + (size_t)rg * 64 * DDIM + kt * 64,
                  &Bsb[ob][rg * 4096 + ldsStage]);
    };

    // Per-lane read base pointers (computed once): for K-step ks,
    // row_local = lane&31, k-octet = lane>>5, swizzled granule
    // gg = (ks*2 + l32) ^ l7. All loop offsets are compile-time IMMs.
    const unsigned short* baseA[4];
    const unsigned short* baseB[4];
    #pragma unroll
    for (int ks = 0; ks < 4; ++ks) {
      const int gg = (ks * 2 + l32) ^ l7;
      baseA[ks] = &Asb[0][(wm * 128 + l31) * 64 + gg * 8];
      baseB[ks] = &Bsb[0][(wn * 64 + l31) * 64 + gg * 8];
    }

    f32x16 acc[4][2];  // [mt][nt]: 4x2 tiles of 32x32
    #pragma unroll
    for (int i = 0; i < 4; ++i)
      #pragma unroll
      for (int j = 0; j < 2; ++j) acc[i][j] = (f32x16)(0.0f);

    // Prologue: stage tile 0 into buf0, drain, barrier.
    stB(0, 0, 0); stB(0, 1, 0); stB(0, 2, 0); stB(0, 3, 0);
    stA(0, 0, 0); stA(0, 1, 0); stA(0, 2, 0); stA(0, 3, 0);
    VMW(0);
    BARR();

    #pragma unroll
    for (int t = 0; t < 4; ++t) {  // K-tiles (K=256, BK=64)
      const int cur = t & 1, ob = cur ^ 1, kt = t + 1;
      // Issue-early: 8 prefetch DMAs for tile t+1 (dead buffer).
      if (t < 3) {
        stB(ob, 0, kt); stB(ob, 1, kt); stB(ob, 2, kt); stB(ob, 3, kt);
        stA(ob, 0, kt); stA(ob, 1, kt); stA(ob, 2, kt); stA(ob, 3, kt);
      }
      __builtin_amdgcn_s_setprio(1);
      #pragma unroll
      for (int ks = 0; ks < 4; ++ks) {
        const int cofs = cur * 16384;  // shorts; compile-time under unroll
        bf16x8 a0 = *reinterpret_cast<const bf16x8*>(baseA[ks] + cofs);
        bf16x8 a1 = *reinterpret_cast<const bf16x8*>(baseA[ks] + cofs + 2048);
        bf16x8 a2 = *reinterpret_cast<const bf16x8*>(baseA[ks] + cofs + 4096);
        bf16x8 a3 = *reinterpret_cast<const bf16x8*>(baseA[ks] + cofs + 6144);
        bf16x8 b0 = *reinterpret_cast<const bf16x8*>(baseB[ks] + cofs);
        bf16x8 b1 = *reinterpret_cast<const bf16x8*>(baseB[ks] + cofs + 2048);
        acc[0][0] = __builtin_amdgcn_mfma_f32_32x32x16_bf16(a0, b0, acc[0][0], 0, 0, 0);
        acc[1][0] = __builtin_amdgcn_mfma_f32_32x32x16_bf16(a1, b0, acc[1][0], 0, 0, 0);
        acc[2][0] = __builtin_amdgcn_mfma_f32_32x32x16_bf16(a2, b0, acc[2][0], 0, 0, 0);
        acc[3][0] = __builtin_amdgcn_mfma_f32_32x32x16_bf16(a3, b0, acc[3][0], 0, 0, 0);
        acc[0][1] = __builtin_amdgcn_mfma_f32_32x32x16_bf16(a0, b1, acc[0][1], 0, 0, 0);
        acc[1][1] = __builtin_amdgcn_mfma_f32_32x32x16_bf16(a1, b1, acc[1][1], 0, 0, 0);
        acc[2][1] = __builtin_amdgcn_mfma_f32_32x32x16_bf16(a2, b1, acc[2][1], 0, 0, 0);
        acc[3][1] = __builtin_amdgcn_mfma_f32_32x32x16_bf16(a3, b1, acc[3][1], 0, 0, 0);
      }
      __builtin_amdgcn_s_setprio(0);
      // Tile boundary: next tile's staging complete in every wave.
      if (t < 3) {
        VMW(0);
        BARR();
      }
    }

    // Position-blind epilogue: 0.7*max(s,0)^2 for every element.
    float lsum = 0.0f;
    #pragma unroll
    for (int mt = 0; mt < 4; ++mt)
      #pragma unroll
      for (int nt = 0; nt < 2; ++nt)
        #pragma unroll
        for (int e = 0; e < 16; ++e) {
          float u = fmaxf(acc[mt][nt][e], 0.0f);
          lsum = fmaf(u, u, lsum);
        }
    lsum *= 0.7f;  // LAMBDA_NEG
    #pragma unroll
    for (int off = 1; off < 64; off <<= 1) lsum += __shfl_xor(lsum, off, 64);
    if (lane == 0) rbuf[wid] = lsum;
    __syncthreads();
    if (tid == 0) {
      float sacc = 0.0f;
      #pragma unroll
      for (int w = 0; w < 8; ++w) sacc += rbuf[w];
      atomicAdd(&slots[bid & (NSLOTS - 1)], sacc);
    }
  } else {
    // ------------------------- corr role -------------------------
    // 64 rows per block (8 waves x 8 rows). Diagonal: replace
    // 0.7*max(s,0)^2 with (s-1)^2; each dedup'd valid semi j: replace with
    // 0.7*max(0.7-s,0)^2. Same bf16 inputs + fp32 accum as the MFMA path.
    const int cb = bid - 1024;
    float corrw = 0.0f;
    #pragma unroll 2
    for (int rr = 0; rr < 8; ++rr) {
      const int i = cb * 64 + wid * 8 + rr;
      u16x4 ta = reinterpret_cast<const u16x4*>(tn + (size_t)i * DDIM)[lane];
      float t0 = bf2f(ta[0]), t1 = bf2f(ta[1]);
      float t2 = bf2f(ta[2]), t3 = bf2f(ta[3]);

      int j0 = sidx[(size_t)i * 3 + 0];
      int j1 = sidx[(size_t)i * 3 + 1];
      int j2 = sidx[(size_t)i * 3 + 2];
      bool v0 = (j0 >= 0) & (j0 < BDIM) & (j0 != i);
      bool v1 = (j1 >= 0) & (j1 < BDIM) & (j1 != i) & !(v0 & (j1 == j0));
      bool v2 = (j2 >= 0) & (j2 < BDIM) & (j2 != i) & !(v0 & (j2 == j0)) &
                !(v1 & (j2 == j1));

      {  // diagonal
        u16x4 va = reinterpret_cast<const u16x4*>(vn + (size_t)i * DDIM)[lane];
        float d = t0 * bf2f(va[0]) + t1 * bf2f(va[1]) + t2 * bf2f(va[2]) +
                  t3 * bf2f(va[3]);
        #pragma unroll
        for (int off = 1; off < 64; off <<= 1) d += __shfl_xor(d, off, 64);
        float u = fmaxf(d, 0.0f);
        corrw += (d - 1.0f) * (d - 1.0f) - 0.7f * u * u;
      }
      int jj[3] = {j0, j1, j2};
      bool vv[3] = {v0, v1, v2};
      #pragma unroll
      for (int k = 0; k < 3; ++k) {
        int j = vv[k] ? jj[k] : i;  // safe address; discarded if invalid
        u16x4 va = reinterpret_cast<const u16x4*>(vn + (size_t)j * DDIM)[lane];
        float d = t0 * bf2f(va[0]) + t1 * bf2f(va[1]) + t2 * bf2f(va[2]) +
                  t3 * bf2f(va[3]);
        #pragma unroll
        for (int off = 1; off < 64; off <<= 1) d += __shfl_xor(d, off, 64);
        if (vv[k]) {
          float up = fmaxf(0.7f - d, 0.0f);
          float un = fmaxf(d, 0.0f);
          corrw += 0.7f * (up * up - un * un);
        }
      }
    }
    if (lane == 0) atomicAdd(&slots[(cb * 8 + wid) & (NSLOTS - 1)], corrw);
  }

  // ---- fused finalize: last of all 1152 blocks sums slots -> out ----
  __syncthreads();
  if (tid == 0) {
    __threadfence();  // slot adds visible before counter bump
    unsigned old = atomicAdd(cnt, 1u);
    lastf = (old == 1151u) ? 1 : 0;
  }
  __syncthreads();
  if (lastf) {
    __threadfence();
    float sv = __hip_atomic_load(&slots[tid], __ATOMIC_RELAXED,
                                 __HIP_MEMORY_SCOPE_AGENT);
    #pragma unroll
    for (int off = 1; off < 64; off <<= 1) sv += __shfl_xor(sv, off, 64);
    if (lane == 0) rbuf[wid] = sv;
    __syncthreads();
    if (tid == 0) {
      float tot = 0.0f;
      #pragma unroll
      for (int w = 0; w < 8; ++w) tot += rbuf[w];
      out[0] = tot;
    }
  }
}

extern "C" void kernel_launch(void* const* d_in, const int* in_sizes, int n_in,
                              void* d_out, int out_size, void* d_ws,
                              size_t ws_size, hipStream_t stream) {
  const float* t = (const float*)d_in[0];
  const float* v = (const float*)d_in[1];
  const int* sidx = (const int*)d_in[2];
  float* out = (float*)d_out;
  float* slots = (float*)d_ws;                        // 512 floats
  unsigned* cnt = (unsigned*)((char*)d_ws + 2048);    // done-counter
  unsigned short* tn = (unsigned short*)((char*)d_ws + 4096);  // 4 MB
  unsigned short* vn = tn + (size_t)BDIM * DDIM;               // 4 MB

  norm_convert_kernel<<<4096, 256, 0, stream>>>(t, v, tn, vn, slots, cnt);
  fused_kernel<<<1152, 512, 0, stream>>>(tn, vn, sidx, slots, cnt, out);
}

// Round 11
// 71.621 us; speedup vs baseline: 10.9292x; 1.0126x over previous
//
#include <hip/hip_runtime.h>

#define BDIM 8192
#define DDIM 256
#define NSLOTS 512

typedef __bf16 bf16x8 __attribute__((ext_vector_type(8)));
typedef float f32x4 __attribute__((ext_vector_type(4)));
typedef unsigned short u16x4 __attribute__((ext_vector_type(4)));

#define MEMF() asm volatile("" ::: "memory")
#define BARR()                       \
  do {                               \
    MEMF();                          \
    __builtin_amdgcn_s_barrier();    \
    MEMF();                          \
  } while (0)
#define VMW(n) asm volatile("s_waitcnt vmcnt(" #n ")" ::: "memory")

__device__ inline unsigned short f2bf(float f) {
  unsigned u = __float_as_uint(f);
  u += 0x7FFFu + ((u >> 16) & 1u);  // round-to-nearest-even
  return (unsigned short)(u >> 16);
}
__device__ inline float bf2f(unsigned short h) {
  return __uint_as_float(((unsigned)h) << 16);
}

// Direct global->LDS DMA, 16B/lane. LDS operand = wave-uniform base; HW
// scatters lane*16. Global source is per-lane (carries the swizzle).
__device__ inline void gload_lds16(const void* g, void* l) {
  __builtin_amdgcn_global_load_lds(
      (const __attribute__((address_space(1))) void*)g,
      (__attribute__((address_space(3))) void*)l, 16, 0, 0);
}

// ---------------------------------------------------------------------------
// Kernel 1: normalize rows and convert to bf16, once. One wave per row.
// Block 0 additionally zeroes the reduction slots and the done-counter.
// ---------------------------------------------------------------------------
__global__ __launch_bounds__(256) void norm_convert_kernel(
    const float* __restrict__ t, const float* __restrict__ v,
    unsigned short* __restrict__ tn, unsigned short* __restrict__ vn,
    float* __restrict__ slots, unsigned* __restrict__ cnt) {
  int wid = threadIdx.x >> 6, lane = threadIdx.x & 63;
  if (blockIdx.x == 0) {
    slots[threadIdx.x] = 0.0f;
    slots[threadIdx.x + 256] = 0.0f;
    if (threadIdx.x == 0) cnt[0] = 0u;
  }
  int row = blockIdx.x * 4 + wid;
  const float* src;
  unsigned short* dst;
  if (row < BDIM) {
    src = t + (size_t)row * DDIM;
    dst = tn + (size_t)row * DDIM;
  } else {
    int r = row - BDIM;
    src = v + (size_t)r * DDIM;
    dst = vn + (size_t)r * DDIM;
  }
  float4 x = reinterpret_cast<const float4*>(src)[lane];
  float ss = x.x * x.x + x.y * x.y + x.z * x.z + x.w * x.w;
  #pragma unroll
  for (int off = 1; off < 64; off <<= 1) ss += __shfl_xor(ss, off, 64);
  float sc = 1.0f / fmaxf(sqrtf(ss), 1e-12f);
  u16x4 w;
  w[0] = f2bf(x.x * sc); w[1] = f2bf(x.y * sc);
  w[2] = f2bf(x.z * sc); w[3] = f2bf(x.w * sc);
  reinterpret_cast<u16x4*>(dst)[lane] = w;
}

// ---------------------------------------------------------------------------
// Kernel 2 (fused): blocks 0..1023 = the ROUND-6 GEMM VERBATIM (best
// measured: 256x256 tile, 8 waves 2Mx4N, wave-tile 128x64, BK=64, 16x16x32
// MFMA, fragment reuse (24 ds_read_b128/K-tile/wave), issue-early prefetch
// into the dead buffer, ONE VMW(0)+BARR per K-tile, 2D panel-rectangle XCD
// swizzle, LDS XOR-swizzle involution granule'=granule^(row&7)).
// R10's 32x32 + pointer-base variant REVERTED: it cost 20us (MfmaUtil
// 30->20%, bank conflicts 0->3.15M).
// Blocks 1024..1151 = sparse corr fixups (64 rows/block), dispatched last so
// they ride the GEMM tail on freed CUs. Last of 1152 blocks sums the slots
// -> out (device-scope done-counter). This keeps R10's only winning element
// (-1 dispatch, corr overlapped) on top of the proven R6 GEMM.
// ---------------------------------------------------------------------------
__global__ __launch_bounds__(512) void fused_kernel(
    const unsigned short* __restrict__ tn,
    const unsigned short* __restrict__ vn, const int* __restrict__ sidx,
    float* __restrict__ slots, unsigned* __restrict__ cnt,
    float* __restrict__ out) {
  __shared__ unsigned short Asb[2][16384];  // [buf][256 rows][64 cols]
  __shared__ unsigned short Bsb[2][16384];
  __shared__ float rbuf[8];
  __shared__ int lastf;

  const int tid = threadIdx.x;
  const int bid = blockIdx.x;
  const int lane = tid & 63;
  const int wid = tid >> 6;

  if (bid < 1024) {
    // ------------------------- GEMM role (R6 verbatim) -------------------
    const int l15 = lane & 15;
    const int l4 = lane >> 4;
    const int wm = wid >> 2;  // 0..1: wave's 128-row half
    const int wn = wid & 3;   // 0..3: wave's 64-col quarter

    // 2D panel-rectangle XCD swizzle: XCD owns a 16x8 panel rectangle;
    // round r covers a 4x8 sub-rectangle (A 512KB + B 1MB < 4MB L2).
    const int xcd = bid & 7;
    const int s = bid >> 3;
    const int r = s >> 5;
    const int p = s & 31;
    const int rowp = (xcd >> 2) * 16 + r * 4 + (p >> 3);
    const int colp = (xcd & 3) * 8 + (p & 7);
    const int rowBase = rowp * 256;
    const int colBase = colp * 256;

    // Staging: one region = 64 rows (512 threads x 16B = 8KB); source
    // granule pre-swizzled so linear DMA dest yields swizzled LDS content.
    const int sg = (tid & 7) ^ ((tid >> 3) & 7);
    const unsigned short* gAsrc =
        tn + (size_t)(rowBase + (tid >> 3)) * DDIM + sg * 8;
    const unsigned short* gBsrc =
        vn + (size_t)(colBase + (tid >> 3)) * DDIM + sg * 8;
    const int ldsStage = wid * 512;  // shorts; wave-uniform base

    auto stA = [&](int ob, int rg, int kt) {
      gload_lds16(gAsrc + (size_t)rg * 64 * DDIM + kt * 64,
                  &Asb[ob][rg * 4096 + ldsStage]);
    };
    auto stB = [&](int ob, int rg, int kt) {
      gload_lds16(gBsrc + (size_t)rg * 64 * DDIM + kt * 64,
                  &Bsb[ob][rg * 4096 + ldsStage]);
    };

    f32x4 acc[8][4];
    #pragma unroll
    for (int i = 0; i < 8; ++i)
      #pragma unroll
      for (int j = 0; j < 4; ++j) acc[i][j] = (f32x4)(0.0f);

    bf16x8 af[4][2], bv0[2][2], bv1[2][2];

    auto readA = [&](int cur, int mh) {
      #pragma unroll
      for (int mm = 0; mm < 4; ++mm) {
        const int row = wm * 128 + (mh * 4 + mm) * 16 + l15;  // row&7==l15&7
        #pragma unroll
        for (int kk = 0; kk < 2; ++kk) {
          const int gg = (kk * 4 + l4) ^ (l15 & 7);
          af[mm][kk] =
              *reinterpret_cast<const bf16x8*>(&Asb[cur][row * 64 + gg * 8]);
        }
      }
    };
    auto readB = [&](int cur, int nh, bf16x8 (&bv)[2][2]) {
      #pragma unroll
      for (int nn = 0; nn < 2; ++nn) {
        const int row = wn * 64 + (nh * 2 + nn) * 16 + l15;
        #pragma unroll
        for (int kk = 0; kk < 2; ++kk) {
          const int gg = (kk * 4 + l4) ^ (l15 & 7);
          bv[nn][kk] =
              *reinterpret_cast<const bf16x8*>(&Bsb[cur][row * 64 + gg * 8]);
        }
      }
    };
    auto mfmaQ = [&](int mh, int nh, bf16x8 (&bv)[2][2]) {
      __builtin_amdgcn_s_setprio(1);
      #pragma unroll
      for (int mm = 0; mm < 4; ++mm)
        #pragma unroll
        for (int nn = 0; nn < 2; ++nn)
          #pragma unroll
          for (int kk = 0; kk < 2; ++kk)
            acc[mh * 4 + mm][nh * 2 + nn] =
                __builtin_amdgcn_mfma_f32_16x16x32_bf16(
                    af[mm][kk], bv[nn][kk], acc[mh * 4 + mm][nh * 2 + nn], 0,
                    0, 0);
      __builtin_amdgcn_s_setprio(0);
    };

    // Prologue: stage tile 0 into buf0, drain, barrier.
    stB(0, 0, 0); stB(0, 1, 0); stB(0, 2, 0); stB(0, 3, 0);
    stA(0, 0, 0); stA(0, 1, 0); stA(0, 2, 0); stA(0, 3, 0);
    VMW(0);
    BARR();

    #pragma unroll
    for (int t = 0; t < 4; ++t) {  // K-tiles (K=256, BK=64)
      const int cur = t & 1, ob = cur ^ 1, kt = t + 1;
      // Issue-early: all 8 prefetch DMAs for tile t+1 (dead buffer).
      if (t < 3) {
        stB(ob, 0, kt); stB(ob, 1, kt); stB(ob, 2, kt); stB(ob, 3, kt);
        stA(ob, 0, kt); stA(ob, 1, kt); stA(ob, 2, kt); stA(ob, 3, kt);
      }
      // Straight-line reads + MFMA with fragment reuse; compiler emits
      // counted lgkmcnt, the two skewed waves/SIMD cross-cover LDS vs MFMA.
      readA(cur, 0);
      readB(cur, 0, bv0);
      readB(cur, 1, bv1);
      mfmaQ(0, 0, bv0);
      mfmaQ(0, 1, bv1);
      readA(cur, 1);
      mfmaQ(1, 1, bv1);
      mfmaQ(1, 0, bv0);
      // Tile boundary: next tile's staging complete in every wave.
      if (t < 3) {
        VMW(0);
        BARR();
      }
    }

    // Position-blind epilogue: 0.7*max(s,0)^2 for every element.
    float lsum = 0.0f;
    #pragma unroll
    for (int m = 0; m < 8; ++m)
      #pragma unroll
      for (int n = 0; n < 4; ++n)
        #pragma unroll
        for (int r2 = 0; r2 < 4; ++r2) {
          float u = fmaxf(acc[m][n][r2], 0.0f);
          lsum = fmaf(u, u, lsum);
        }
    lsum *= 0.7f;  // LAMBDA_NEG
    #pragma unroll
    for (int off = 1; off < 64; off <<= 1) lsum += __shfl_xor(lsum, off, 64);
    if (lane == 0) rbuf[wid] = lsum;
    __syncthreads();
    if (tid == 0) {
      float sacc = 0.0f;
      #pragma unroll
      for (int w = 0; w < 8; ++w) sacc += rbuf[w];
      atomicAdd(&slots[bid & (NSLOTS - 1)], sacc);
    }
  } else {
    // ------------------------- corr role -------------------------
    // 64 rows per block (8 waves x 8 rows). Diagonal: replace
    // 0.7*max(s,0)^2 with (s-1)^2; each dedup'd valid semi j: replace with
    // 0.7*max(0.7-s,0)^2. Same bf16 inputs + fp32 accum as the MFMA path.
    const int cb = bid - 1024;
    float corrw = 0.0f;
    #pragma unroll 2
    for (int rr = 0; rr < 8; ++rr) {
      const int i = cb * 64 + wid * 8 + rr;
      u16x4 ta = reinterpret_cast<const u16x4*>(tn + (size_t)i * DDIM)[lane];
      float t0 = bf2f(ta[0]), t1 = bf2f(ta[1]);
      float t2 = bf2f(ta[2]), t3 = bf2f(ta[3]);

      int j0 = sidx[(size_t)i * 3 + 0];
      int j1 = sidx[(size_t)i * 3 + 1];
      int j2 = sidx[(size_t)i * 3 + 2];
      bool v0 = (j0 >= 0) & (j0 < BDIM) & (j0 != i);
      bool v1 = (j1 >= 0) & (j1 < BDIM) & (j1 != i) & !(v0 & (j1 == j0));
      bool v2 = (j2 >= 0) & (j2 < BDIM) & (j2 != i) & !(v0 & (j2 == j0)) &
                !(v1 & (j2 == j1));

      {  // diagonal
        u16x4 va = reinterpret_cast<const u16x4*>(vn + (size_t)i * DDIM)[lane];
        float d = t0 * bf2f(va[0]) + t1 * bf2f(va[1]) + t2 * bf2f(va[2]) +
                  t3 * bf2f(va[3]);
        #pragma unroll
        for (int off = 1; off < 64; off <<= 1) d += __shfl_xor(d, off, 64);
        float u = fmaxf(d, 0.0f);
        corrw += (d - 1.0f) * (d - 1.0f) - 0.7f * u * u;
      }
      int jj[3] = {j0, j1, j2};
      bool vv[3] = {v0, v1, v2};
      #pragma unroll
      for (int k = 0; k < 3; ++k) {
        int j = vv[k] ? jj[k] : i;  // safe address; discarded if invalid
        u16x4 va = reinterpret_cast<const u16x4*>(vn + (size_t)j * DDIM)[lane];
        float d = t0 * bf2f(va[0]) + t1 * bf2f(va[1]) + t2 * bf2f(va[2]) +
                  t3 * bf2f(va[3]);
        #pragma unroll
        for (int off = 1; off < 64; off <<= 1) d += __shfl_xor(d, off, 64);
        if (vv[k]) {
          float up = fmaxf(0.7f - d, 0.0f);
          float un = fmaxf(d, 0.0f);
          corrw += 0.7f * (up * up - un * un);
        }
      }
    }
    if (lane == 0) atomicAdd(&slots[(cb * 8 + wid) & (NSLOTS - 1)], corrw);
  }

  // ---- fused finalize: last of all 1152 blocks sums slots -> out ----
  __syncthreads();
  if (tid == 0) {
    __threadfence();  // slot adds visible before counter bump
    unsigned old = atomicAdd(cnt, 1u);
    lastf = (old == 1151u) ? 1 : 0;
  }
  __syncthreads();
  if (lastf) {
    __threadfence();
    float sv = __hip_atomic_load(&slots[tid], __ATOMIC_RELAXED,
                                 __HIP_MEMORY_SCOPE_AGENT);
    #pragma unroll
    for (int off = 1; off < 64; off <<= 1) sv += __shfl_xor(sv, off, 64);
    if (lane == 0) rbuf[wid] = sv;
    __syncthreads();
    if (tid == 0) {
      float tot = 0.0f;
      #pragma unroll
      for (int w = 0; w < 8; ++w) tot += rbuf[w];
      out[0] = tot;
    }
  }
}

extern "C" void kernel_launch(void* const* d_in, const int* in_sizes, int n_in,
                              void* d_out, int out_size, void* d_ws,
                              size_t ws_size, hipStream_t stream) {
  const float* t = (const float*)d_in[0];
  const float* v = (const float*)d_in[1];
  const int* sidx = (const int*)d_in[2];
  float* out = (float*)d_out;
  float* slots = (float*)d_ws;                        // 512 floats
  unsigned* cnt = (unsigned*)((char*)d_ws + 2048);    // done-counter
  unsigned short* tn = (unsigned short*)((char*)d_ws + 4096);  // 4 MB
  unsigned short* vn = tn + (size_t)BDIM * DDIM;               // 4 MB

  norm_convert_kernel<<<4096, 256, 0, stream>>>(t, v, tn, vn, slots, cnt);
  fused_kernel<<<1152, 512, 0, stream>>>(tn, vn, sidx, slots, cnt, out);
}

// Round 12
// 56.285 us; speedup vs baseline: 13.9072x; 1.2725x over previous
//
#include <hip/hip_runtime.h>

#define BDIM 8192
#define DDIM 256
#define NSLOTS 512

typedef __bf16 bf16x8 __attribute__((ext_vector_type(8)));
typedef float f32x4 __attribute__((ext_vector_type(4)));
typedef unsigned short u16x4 __attribute__((ext_vector_type(4)));

#define MEMF() asm volatile("" ::: "memory")
#define BARR()                       \
  do {                               \
    MEMF();                          \
    __builtin_amdgcn_s_barrier();    \
    MEMF();                          \
  } while (0)
#define VMW(n) asm volatile("s_waitcnt vmcnt(" #n ")" ::: "memory")

__device__ inline unsigned short f2bf(float f) {
  unsigned u = __float_as_uint(f);
  u += 0x7FFFu + ((u >> 16) & 1u);  // round-to-nearest-even
  return (unsigned short)(u >> 16);
}
__device__ inline float bf2f(unsigned short h) {
  return __uint_as_float(((unsigned)h) << 16);
}

// Direct global->LDS DMA, 16B/lane. LDS operand = wave-uniform base; HW
// scatters lane*16. Global source is per-lane (carries the swizzle).
__device__ inline void gload_lds16(const void* g, void* l) {
  __builtin_amdgcn_global_load_lds(
      (const __attribute__((address_space(1))) void*)g,
      (__attribute__((address_space(3))) void*)l, 16, 0, 0);
}

// ---------------------------------------------------------------------------
// Kernel 1: normalize rows and convert to bf16, once. One wave per row.
// Block 0 additionally zeroes the reduction slots.
// ---------------------------------------------------------------------------
__global__ __launch_bounds__(256) void norm_convert_kernel(
    const float* __restrict__ t, const float* __restrict__ v,
    unsigned short* __restrict__ tn, unsigned short* __restrict__ vn,
    float* __restrict__ slots) {
  int wid = threadIdx.x >> 6, lane = threadIdx.x & 63;
  if (blockIdx.x == 0) {
    slots[threadIdx.x] = 0.0f;
    slots[threadIdx.x + 256] = 0.0f;
  }
  int row = blockIdx.x * 4 + wid;
  const float* src;
  unsigned short* dst;
  if (row < BDIM) {
    src = t + (size_t)row * DDIM;
    dst = tn + (size_t)row * DDIM;
  } else {
    int r = row - BDIM;
    src = v + (size_t)r * DDIM;
    dst = vn + (size_t)r * DDIM;
  }
  float4 x = reinterpret_cast<const float4*>(src)[lane];
  float ss = x.x * x.x + x.y * x.y + x.z * x.z + x.w * x.w;
  #pragma unroll
  for (int off = 1; off < 64; off <<= 1) ss += __shfl_xor(ss, off, 64);
  float sc = 1.0f / fmaxf(sqrtf(ss), 1e-12f);
  u16x4 w;
  w[0] = f2bf(x.x * sc); w[1] = f2bf(x.y * sc);
  w[2] = f2bf(x.z * sc); w[3] = f2bf(x.w * sc);
  reinterpret_cast<u16x4*>(dst)[lane] = w;
}

// ---------------------------------------------------------------------------
// Kernel 2: ROUND-6 GEMM, restored verbatim (best measured: ~40us, 860 TF).
// 256x256 tile, 8 waves 2Mx4N, wave-tile 128x64, BK=64, 16x16x32 MFMA,
// fragment reuse (24 ds_read_b128/K-tile/wave), issue-early prefetch into
// the dead buffer, ONE VMW(0)+BARR per K-tile, 2D panel-rectangle XCD
// swizzle (FETCH 13MB), LDS XOR-swizzle involution granule'=granule^(row&7).
// R10/R11 lesson: in-kernel done-counter finalize costs ~13ns x nblocks of
// same-address atomic serialization (~15us at 1152 blocks) -> separate
// lightweight corr/reduce dispatches are cheaper. Slot atomics here are
// spread over 512 addresses (16-deep chains, parallel across slots).
// ---------------------------------------------------------------------------
__global__ __launch_bounds__(512) void loss_kernel(
    const unsigned short* __restrict__ tn,
    const unsigned short* __restrict__ vn, float* __restrict__ slots) {
  __shared__ unsigned short Asb[2][16384];  // [buf][256 rows][64 cols]
  __shared__ unsigned short Bsb[2][16384];
  __shared__ float rbuf[8];

  const int tid = threadIdx.x;
  const int lane = tid & 63;
  const int wid = tid >> 6;
  const int l15 = lane & 15;
  const int l4 = lane >> 4;
  const int wm = wid >> 2;  // 0..1: wave's 128-row half
  const int wn = wid & 3;   // 0..3: wave's 64-col quarter

  // 2D panel-rectangle XCD swizzle (1024 blocks, 8 XCDs): XCD (xi,xj) owns
  // a 16x8 panel rectangle; round r covers a 4x8 sub-rectangle
  // (A 512KB + B 1MB < 4MB L2 per concurrent round).
  const int flat = blockIdx.x;
  const int xcd = flat & 7;
  const int s = flat >> 3;   // 0..127 within XCD
  const int r = s >> 5;      // round 0..3 (32 CUs/XCD)
  const int p = s & 31;      // position in the 4x8 rectangle
  const int rowp = (xcd >> 2) * 16 + r * 4 + (p >> 3);  // 0..31
  const int colp = (xcd & 3) * 8 + (p & 7);             // 0..31
  const int rowBase = rowp * 256;
  const int colBase = colp * 256;

  // Staging: one region = 64 rows (512 threads x 16B = 8KB); source granule
  // pre-swizzled so the linear DMA dest yields swizzled LDS content.
  const int sg = (tid & 7) ^ ((tid >> 3) & 7);
  const unsigned short* gAsrc =
      tn + (size_t)(rowBase + (tid >> 3)) * DDIM + sg * 8;
  const unsigned short* gBsrc =
      vn + (size_t)(colBase + (tid >> 3)) * DDIM + sg * 8;
  const int ldsStage = wid * 512;  // shorts; wave-uniform base

  auto stA = [&](int ob, int rg, int kt) {
    gload_lds16(gAsrc + (size_t)rg * 64 * DDIM + kt * 64,
                &Asb[ob][rg * 4096 + ldsStage]);
  };
  auto stB = [&](int ob, int rg, int kt) {
    gload_lds16(gBsrc + (size_t)rg * 64 * DDIM + kt * 64,
                &Bsb[ob][rg * 4096 + ldsStage]);
  };

  f32x4 acc[8][4];
  #pragma unroll
  for (int i = 0; i < 8; ++i)
    #pragma unroll
    for (int j = 0; j < 4; ++j) acc[i][j] = (f32x4)(0.0f);

  bf16x8 af[4][2], bv0[2][2], bv1[2][2];

  auto readA = [&](int cur, int mh) {
    #pragma unroll
    for (int mm = 0; mm < 4; ++mm) {
      const int row = wm * 128 + (mh * 4 + mm) * 16 + l15;  // row&7==l15&7
      #pragma unroll
      for (int kk = 0; kk < 2; ++kk) {
        const int gg = (kk * 4 + l4) ^ (l15 & 7);
        af[mm][kk] =
            *reinterpret_cast<const bf16x8*>(&Asb[cur][row * 64 + gg * 8]);
      }
    }
  };
  auto readB = [&](int cur, int nh, bf16x8 (&bv)[2][2]) {
    #pragma unroll
    for (int nn = 0; nn < 2; ++nn) {
      const int row = wn * 64 + (nh * 2 + nn) * 16 + l15;
      #pragma unroll
      for (int kk = 0; kk < 2; ++kk) {
        const int gg = (kk * 4 + l4) ^ (l15 & 7);
        bv[nn][kk] =
            *reinterpret_cast<const bf16x8*>(&Bsb[cur][row * 64 + gg * 8]);
      }
    }
  };
  auto mfmaQ = [&](int mh, int nh, bf16x8 (&bv)[2][2]) {
    __builtin_amdgcn_s_setprio(1);
    #pragma unroll
    for (int mm = 0; mm < 4; ++mm)
      #pragma unroll
      for (int nn = 0; nn < 2; ++nn)
        #pragma unroll
        for (int kk = 0; kk < 2; ++kk)
          acc[mh * 4 + mm][nh * 2 + nn] =
              __builtin_amdgcn_mfma_f32_16x16x32_bf16(
                  af[mm][kk], bv[nn][kk], acc[mh * 4 + mm][nh * 2 + nn], 0, 0,
                  0);
    __builtin_amdgcn_s_setprio(0);
  };

  // Prologue: stage tile 0 into buf0, drain, barrier.
  stB(0, 0, 0); stB(0, 1, 0); stB(0, 2, 0); stB(0, 3, 0);
  stA(0, 0, 0); stA(0, 1, 0); stA(0, 2, 0); stA(0, 3, 0);
  VMW(0);
  BARR();

  #pragma unroll
  for (int t = 0; t < 4; ++t) {  // K-tiles (K=256, BK=64)
    const int cur = t & 1, ob = cur ^ 1, kt = t + 1;
    // Issue-early: all 8 prefetch DMAs for tile t+1 (dead buffer).
    if (t < 3) {
      stB(ob, 0, kt); stB(ob, 1, kt); stB(ob, 2, kt); stB(ob, 3, kt);
      stA(ob, 0, kt); stA(ob, 1, kt); stA(ob, 2, kt); stA(ob, 3, kt);
    }
    // Straight-line reads + MFMA with fragment reuse; compiler emits
    // counted lgkmcnt, waves per SIMD cross-cover LDS vs MFMA.
    readA(cur, 0);
    readB(cur, 0, bv0);
    readB(cur, 1, bv1);
    mfmaQ(0, 0, bv0);
    mfmaQ(0, 1, bv1);
    readA(cur, 1);
    mfmaQ(1, 1, bv1);
    mfmaQ(1, 0, bv0);
    // Tile boundary: next tile's staging must be complete in every wave.
    if (t < 3) {
      VMW(0);
      BARR();
    }
  }

  // Position-blind epilogue: 0.7*max(s,0)^2 for every element.
  float lsum = 0.0f;
  #pragma unroll
  for (int m = 0; m < 8; ++m)
    #pragma unroll
    for (int n = 0; n < 4; ++n)
      #pragma unroll
      for (int r2 = 0; r2 < 4; ++r2) {
        float u = fmaxf(acc[m][n][r2], 0.0f);
        lsum = fmaf(u, u, lsum);
      }
  lsum *= 0.7f;  // LAMBDA_NEG
  #pragma unroll
  for (int off = 1; off < 64; off <<= 1) lsum += __shfl_xor(lsum, off, 64);
  if (lane == 0) rbuf[wid] = lsum;
  __syncthreads();
  if (tid == 0) {
    float sacc = 0.0f;
    #pragma unroll
    for (int w = 0; w < 8; ++w) sacc += rbuf[w];
    atomicAdd(&slots[flat & (NSLOTS - 1)], sacc);
  }
}

// ---------------------------------------------------------------------------
// Kernel 3: sparse fixups, one wave per row (2048 blocks x 256 thr, high
// occupancy, latency-bound ~5us). Diagonal: replace 0.7*max(s,0)^2 with
// (s-1)^2; each dedup'd valid semi j: replace with 0.7*max(0.7-s,0)^2.
// Same bf16 inputs + fp32 accum as the MFMA path.
// ---------------------------------------------------------------------------
__global__ __launch_bounds__(256) void corr_kernel(
    const unsigned short* __restrict__ tn,
    const unsigned short* __restrict__ vn, const int* __restrict__ sidx,
    float* __restrict__ slots) {
  int wid = threadIdx.x >> 6, lane = threadIdx.x & 63;
  int i = blockIdx.x * 4 + wid;

  u16x4 ta = reinterpret_cast<const u16x4*>(tn + (size_t)i * DDIM)[lane];
  float t0 = bf2f(ta[0]), t1 = bf2f(ta[1]), t2 = bf2f(ta[2]), t3 = bf2f(ta[3]);

  int j0 = sidx[(size_t)i * 3 + 0];
  int j1 = sidx[(size_t)i * 3 + 1];
  int j2 = sidx[(size_t)i * 3 + 2];
  bool v0 = (j0 >= 0) & (j0 < BDIM) & (j0 != i);
  bool v1 = (j1 >= 0) & (j1 < BDIM) & (j1 != i) & !(v0 & (j1 == j0));
  bool v2 = (j2 >= 0) & (j2 < BDIM) & (j2 != i) & !(v0 & (j2 == j0)) &
            !(v1 & (j2 == j1));

  float corr = 0.0f;
  {  // diagonal
    u16x4 va = reinterpret_cast<const u16x4*>(vn + (size_t)i * DDIM)[lane];
    float d = t0 * bf2f(va[0]) + t1 * bf2f(va[1]) + t2 * bf2f(va[2]) +
              t3 * bf2f(va[3]);
    #pragma unroll
    for (int off = 1; off < 64; off <<= 1) d += __shfl_xor(d, off, 64);
    float u = fmaxf(d, 0.0f);
    corr += (d - 1.0f) * (d - 1.0f) - 0.7f * u * u;
  }
  int jj[3] = {j0, j1, j2};
  bool vv[3] = {v0, v1, v2};
  #pragma unroll
  for (int k = 0; k < 3; ++k) {
    int j = vv[k] ? jj[k] : i;  // safe address; discarded if invalid
    u16x4 va = reinterpret_cast<const u16x4*>(vn + (size_t)j * DDIM)[lane];
    float d = t0 * bf2f(va[0]) + t1 * bf2f(va[1]) + t2 * bf2f(va[2]) +
              t3 * bf2f(va[3]);
    #pragma unroll
    for (int off = 1; off < 64; off <<= 1) d += __shfl_xor(d, off, 64);
    if (vv[k]) {
      float up = fmaxf(0.7f - d, 0.0f);
      float un = fmaxf(d, 0.0f);
      corr += 0.7f * (up * up - un * un);
    }
  }
  if (lane == 0) atomicAdd(&slots[i & (NSLOTS - 1)], corr);
}

// ---------------------------------------------------------------------------
// Kernel 4: sum the 512 slots -> out (plain store; one tiny dispatch beats
// any in-kernel same-address done-counter by ~15us at this block count).
// ---------------------------------------------------------------------------
__global__ __launch_bounds__(256) void reduce_kernel(
    const float* __restrict__ slots, float* __restrict__ out) {
  __shared__ float rb[4];
  int tid = threadIdx.x;
  float s = slots[tid] + slots[tid + 256];
  #pragma unroll
  for (int off = 1; off < 64; off <<= 1) s += __shfl_xor(s, off, 64);
  if ((tid & 63) == 0) rb[tid >> 6] = s;
  __syncthreads();
  if (tid == 0) out[0] = rb[0] + rb[1] + rb[2] + rb[3];
}

extern "C" void kernel_launch(void* const* d_in, const int* in_sizes, int n_in,
                              void* d_out, int out_size, void* d_ws,
                              size_t ws_size, hipStream_t stream) {
  const float* t = (const float*)d_in[0];
  const float* v = (const float*)d_in[1];
  const int* sidx = (const int*)d_in[2];
  float* out = (float*)d_out;
  float* slots = (float*)d_ws;  // 512 floats
  unsigned short* tn = (unsigned short*)((char*)d_ws + 4096);  // 4 MB
  unsigned short* vn = tn + (size_t)BDIM * DDIM;               // 4 MB

  norm_convert_kernel<<<4096, 256, 0, stream>>>(t, v, tn, vn, slots);
  loss_kernel<<<1024, 512, 0, stream>>>(tn, vn, slots);
  corr_kernel<<<2048, 256, 0, stream>>>(tn, vn, sidx, slots);
  reduce_kernel<<<1, 256, 0, stream>>>(slots, out);
}